// Round 14
// baseline (115.326 us; speedup 1.0000x reference)
//
#include <hip/hip_runtime.h>
#include <cstddef>

#define NN 4096   // nodes
#define NL 8      // layers
#define ND 128    // feature dim

#define CHUNK 128   // j's per block (256 blocks = 1/CU)
#define BATCH 16    // GEMV slots per batch

typedef int   int4v   __attribute__((ext_vector_type(4)));
typedef float float4v __attribute__((ext_vector_type(4)));

// ---------------------------------------------------------------------------
// Round-11 base (96.1us) + wave specialization: waves 0-6 start the chunk-row
// stream AT KERNEL ENTRY (parity NT/plain split); wave 7 concurrently does the
// whole irregular prologue wave-synchronously (zero __syncthreads): per-lane
// descending src scan (2 j's/lane, 8-row unrolled coalesced loads), in-wave
// dedup (shuffle prefix scan), src-row sums (FULL row: 16 x 64 x int4),
// feature staging. One join, then scales + GEMV + scaled NT stores.
// ---------------------------------------------------------------------------
__global__ __launch_bounds__(512, 2) void fused_kernel(
    const float* __restrict__ feature, const float* __restrict__ W,
    const int* __restrict__ adj, float* __restrict__ out) {
  __shared__ int      s_src[CHUNK];
  __shared__ unsigned s_mask[NN / 32];   // 128 words
  __shared__ int      s_ps[NN / 32];
  __shared__ int      s_list[CHUNK];
  __shared__ int      s_smap[CHUNK];
  __shared__ float    s_scj[CHUNK];
  __shared__ float    s_deg[2 * CHUNK];
  __shared__ float    s_fb[BATCH][ND];
  __shared__ float    s_wf[BATCH][ND];

  const int t = threadIdx.x;
  const int l = blockIdx.y;
  const int jbase = blockIdx.x * CHUNK;
  const int* __restrict__ Al = adj + (size_t)l * NN * NN;
  const int wv = t >> 6;
  const int lane = t & 63;

  if (wv < 7) {
    // ======== waves 0-6: chunk-row sums, streaming starts immediately ======
    for (int r = wv; r < CHUNK; r += 7) {
      const int row = jbase + r;
      const int4v* __restrict__ p =
          reinterpret_cast<const int4v*>(Al + (size_t)row * NN);
      int s = 0;
      if (row & 1) {
#pragma unroll
        for (int k = 0; k < 16; ++k) {
          int4v v = __builtin_nontemporal_load(&p[lane + k * 64]);
          s += v.x + v.y + v.z + v.w;
        }
      } else {
#pragma unroll
        for (int k = 0; k < 16; ++k) {
          int4v v = p[lane + k * 64];
          s += v.x + v.y + v.z + v.w;
        }
      }
      for (int off = 32; off > 0; off >>= 1) s += __shfl_down(s, off, 64);
      if (lane == 0) s_deg[r] = (float)s + 1.0f;
    }
  } else {
    // ======== wave 7: scan -> dedup -> src degs -> fb staging ========
    const int j0 = jbase + lane;
    const int j1 = jbase + 64 + lane;
    int src0 = j0, src1 = j1;
    bool f0 = false, f1 = false;
    int itop = NN - 1;
    for (;;) {
      int a0[8], a1[8];
#pragma unroll
      for (int r = 0; r < 8; ++r) {
        const int i = itop - r;
        a0[r] = (i > j0) ? Al[(size_t)i * NN + j0] : 0;
        a1[r] = (i > j1) ? Al[(size_t)i * NN + j1] : 0;
      }
#pragma unroll
      for (int r = 0; r < 8; ++r) {
        const int i = itop - r;
        if (!f0 && a0[r] != 0 && i > j0) { src0 = i; f0 = true; }
        if (!f1 && a1[r] != 0 && i > j1) { src1 = i; f1 = true; }
      }
      itop -= 8;
      if (__all((f0 || itop <= j0) && (f1 || itop <= j1))) break;
    }
    s_src[lane] = src0;
    s_src[lane + 64] = src1;
    s_mask[2 * lane] = 0u;
    s_mask[2 * lane + 1] = 0u;
    __threadfence_block();
    atomicOr(&s_mask[src0 >> 5], 1u << (src0 & 31));
    atomicOr(&s_mask[src1 >> 5], 1u << (src1 & 31));
    __threadfence_block();

    // in-wave prefix scan over 128 word popcounts (2 words/lane)
    const unsigned m0 = s_mask[2 * lane];
    const unsigned m1 = s_mask[2 * lane + 1];
    const int c = __popc(m0) + __popc(m1);
    int sc = c;
    for (int off = 1; off < 64; off <<= 1) {
      int v = __shfl_up(sc, off, 64);
      if (lane >= off) sc += v;
    }
    const int excl = sc - c;
    const int ps0 = excl + __popc(m0);
    s_ps[2 * lane] = ps0;
    s_ps[2 * lane + 1] = ps0 + __popc(m1);
    // extract set bits -> list
    int pos = excl;
    unsigned mm = m0;
    while (mm) {
      const int b = __ffs(mm) - 1;
      mm &= mm - 1;
      s_list[pos++] = ((2 * lane) << 5) | b;
    }
    mm = m1;
    while (mm) {
      const int b = __ffs(mm) - 1;
      mm &= mm - 1;
      s_list[pos++] = ((2 * lane + 1) << 5) | b;
    }
    const int cnt = __shfl(sc, 63, 64);
    __threadfence_block();
    // smap for this lane's 2 j's
    {
      const int v = src0, w = v >> 5;
      const int base = (w > 0) ? s_ps[w - 1] : 0;
      s_smap[lane] = base + __popc(s_mask[w] & ((1u << (v & 31)) - 1));
    }
    {
      const int v = src1, w = v >> 5;
      const int base = (w > 0) ? s_ps[w - 1] : 0;
      s_smap[lane + 64] = base + __popc(s_mask[w] & ((1u << (v & 31)) - 1));
    }
    __threadfence_block();
    // src-row sums: FULL row = 16 iters x 64 lanes x int4 (bug was k<4)
    for (int r = 0; r < cnt; ++r) {
      const int4v* __restrict__ p =
          reinterpret_cast<const int4v*>(Al + (size_t)s_list[r] * NN);
      int s = 0;
#pragma unroll
      for (int k = 0; k < 16; ++k) {
        int4v v = p[lane + k * 64];
        s += v.x + v.y + v.z + v.w;
      }
      for (int off = 32; off > 0; off >>= 1) s += __shfl_down(s, off, 64);
      if (lane == 0) s_deg[CHUNK + r] = (float)s + 1.0f;
    }
    // stage feature rows for the first batch
    const int nb0 = min(cnt, BATCH);
    for (int idx = lane; idx < nb0 * 32; idx += 64) {
      const int k = idx >> 5, q = idx & 31;
      reinterpret_cast<float4v*>(s_fb[k])[q] =
          reinterpret_cast<const float4v*>(
              feature + ((size_t)s_list[k] * NL + l) * ND)[q];
    }
  }
  __syncthreads();

  const int cnt = s_ps[127];
  const int nb0 = min(cnt, BATCH);
  if (t < CHUNK)
    s_scj[t] = rsqrtf(s_deg[t] * s_deg[CHUNK + s_smap[t]]);

  // ---- GEMV batch 0 (fb pre-staged by wave 7) ----
  const int d = t & 127;
  const int quarter = t >> 7;
  const float4v* __restrict__ Wd =
      reinterpret_cast<const float4v*>(W + (size_t)d * ND);
#pragma unroll
  for (int kk = 0; kk < 4; ++kk) {
    const int k = quarter * 4 + kk;
    if (k < nb0) {
      float4v a4 = {0.f, 0.f, 0.f, 0.f};
#pragma unroll
      for (int q = 0; q < 32; ++q)
        a4 += Wd[q] * reinterpret_cast<const float4v*>(s_fb[k])[q];
      s_wf[k][d] = a4.x + a4.y + a4.z + a4.w;
    }
  }
  __syncthreads();

  for (int idx = t; idx < CHUNK * 32; idx += 512) {
    const int r = idx >> 5, q = idx & 31;
    const int sl = s_smap[r];
    if (sl < nb0) {
      const float sc = s_scj[r];
      float4v v = reinterpret_cast<const float4v*>(s_wf[sl])[q];
      v.x *= sc; v.y *= sc; v.z *= sc; v.w *= sc;
      __builtin_nontemporal_store(
          v, reinterpret_cast<float4v*>(out) +
                 ((size_t)(jbase + r) * NL + l) * 32 + q);
    }
  }

  // ---- rare fallback: cnt > 16 (adversarial adj), batched like round 11 ----
  for (int b0 = BATCH; b0 < cnt; b0 += BATCH) {
    const int nb = min(BATCH, cnt - b0);
    __syncthreads();
    for (int idx = t; idx < nb * 32; idx += 512) {
      const int k = idx >> 5, q = idx & 31;
      reinterpret_cast<float4v*>(s_fb[k])[q] =
          reinterpret_cast<const float4v*>(
              feature + ((size_t)s_list[b0 + k] * NL + l) * ND)[q];
    }
    __syncthreads();
#pragma unroll
    for (int kk = 0; kk < 4; ++kk) {
      const int k = quarter * 4 + kk;
      if (k < nb) {
        float4v a4 = {0.f, 0.f, 0.f, 0.f};
#pragma unroll
        for (int q = 0; q < 32; ++q)
          a4 += Wd[q] * reinterpret_cast<const float4v*>(s_fb[k])[q];
        s_wf[k][d] = a4.x + a4.y + a4.z + a4.w;
      }
    }
    __syncthreads();
    for (int idx = t; idx < CHUNK * 32; idx += 512) {
      const int r = idx >> 5, q = idx & 31;
      const int sl = s_smap[r] - b0;
      if (sl >= 0 && sl < nb) {
        const float sc = s_scj[r];
        float4v v = reinterpret_cast<const float4v*>(s_wf[sl])[q];
        v.x *= sc; v.y *= sc; v.z *= sc; v.w *= sc;
        __builtin_nontemporal_store(
            v, reinterpret_cast<float4v*>(out) +
                   ((size_t)(jbase + r) * NL + l) * 32 + q);
      }
    }
  }
}

// ---------------------------------------------------------------------------
extern "C" void kernel_launch(void* const* d_in, const int* in_sizes, int n_in,
                              void* d_out, int out_size, void* d_ws,
                              size_t ws_size, hipStream_t stream) {
  const float* feature = (const float*)d_in[0];   // [NN, NL, ND] f32
  const float* W       = (const float*)d_in[1];   // [ND, ND]     f32
  const int*   adj     = (const int*)d_in[2];     // [NL, NN, NN] i32
  float* out = (float*)d_out;                     // [NN, NL, ND] f32

  fused_kernel<<<dim3(NN / CHUNK, NL), 512, 0, stream>>>(feature, W, adj, out);
}